// Round 2
// baseline (535.700 us; speedup 1.0000x reference)
//
#include <hip/hip_runtime.h>

#define NB 8
#define CC 256
#define NN 2304
#define TK 32

typedef __attribute__((ext_vector_type(8))) short short8;
typedef __attribute__((ext_vector_type(4))) float f32x4;
typedef __attribute__((ext_vector_type(4))) unsigned short us4;

#define MFMA16(a, b, c) __builtin_amdgcn_mfma_f32_16x16x32_bf16((a), (b), (c), 0, 0, 0)

__device__ __forceinline__ unsigned short f2bf(float f) {
    unsigned int u = __float_as_uint(f);
    u = (u + 0x7fffu + ((u >> 16) & 1u)) >> 16;
    return (unsigned short)u;
}
__device__ __forceinline__ float bf2f(unsigned short h) {
    return __uint_as_float(((unsigned int)h) << 16);
}

// ---- fold output projection + BN into per-channel scale/bias ----
__global__ void prep_s2(const float* __restrict__ w_o, const float* __restrict__ b_o,
                        const float* __restrict__ gam, const float* __restrict__ bet,
                        const float* __restrict__ mea, const float* __restrict__ var,
                        float* __restrict__ s2b2) {
    int c = threadIdx.x;
    float inv = gam[c] * rsqrtf(var[c] + 1e-5f);
    s2b2[c]      = w_o[c] * inv;
    s2b2[CC + c] = b_o[c] * inv + bet[c] - mea[c] * inv;
}

// ---- transpose + project x -> Q(hi/lo), K(hi/lo), layout (B, N, C) bf16 ----
__global__ __launch_bounds__(256) void prep_qk(
    const float* __restrict__ x,
    const float* __restrict__ w_t, const float* __restrict__ b_t,
    const float* __restrict__ w_p, const float* __restrict__ b_p,
    unsigned short* __restrict__ qhi, unsigned short* __restrict__ qlo,
    unsigned short* __restrict__ khi, unsigned short* __restrict__ klo) {
    __shared__ float tile[64][65];
    int bid = blockIdx.x;
    int b  = bid / 144;            // 36 n-tiles * 4 c-tiles
    int r  = bid % 144;
    int n0 = (r / 4) * 64;
    int c0 = (r % 4) * 64;
    int t  = threadIdx.x;
    int tx = t & 15, ty = t >> 4;

#pragma unroll
    for (int i = 0; i < 4; ++i) {
        int c = ty + i * 16;
        const float4 v = *(const float4*)&x[(size_t)(b * CC + c0 + c) * NN + n0 + tx * 4];
        tile[c][tx * 4 + 0] = v.x;
        tile[c][tx * 4 + 1] = v.y;
        tile[c][tx * 4 + 2] = v.z;
        tile[c][tx * 4 + 3] = v.w;
    }
    __syncthreads();
#pragma unroll
    for (int i = 0; i < 4; ++i) {
        int n = ty + i * 16;
        us4 qh, ql, kh, kl;
#pragma unroll
        for (int k = 0; k < 4; ++k) {
            int c = c0 + tx * 4 + k;
            float v  = tile[tx * 4 + k][n];
            float qv = v * w_t[c] + b_t[c];
            unsigned short h = f2bf(qv);
            qh[k] = h; ql[k] = f2bf(qv - bf2f(h));
            float kv = v * w_p[c] + b_p[c];
            h = f2bf(kv);
            kh[k] = h; kl[k] = f2bf(kv - bf2f(h));
        }
        size_t off = (size_t)(b * NN + n0 + n) * CC + c0 + tx * 4;
        *(us4*)&qhi[off] = qh;
        *(us4*)&qlo[off] = ql;
        *(us4*)&khi[off] = kh;
        *(us4*)&klo[off] = kl;
    }
}

// ---- flash attention: 4 waves x 16 q-rows, TK=32 key tiles ----
__global__ __launch_bounds__(256, 2) void attn(
    const float* __restrict__ x,
    const unsigned short* __restrict__ qhi, const unsigned short* __restrict__ qlo,
    const unsigned short* __restrict__ khi, const unsigned short* __restrict__ klo,
    const float* __restrict__ w_g, const float* __restrict__ b_g,
    const float* __restrict__ s2b2,
    float* __restrict__ out) {
    // K tiles padded +8 ushorts/row (16B) to break the stride-512B bank pathology
    __shared__ __align__(16) unsigned short kh_s[TK][264];
    __shared__ __align__(16) unsigned short kl_s[TK][264];
    __shared__ __align__(16) unsigned short vt_s[CC][40];   // V^T: [c][m], stride 40
    __shared__ __align__(16) unsigned short p_s[4][16][40]; // per-wave P tile

    int bid = blockIdx.x;
    int b  = bid / 36;
    int n0 = (bid % 36) * 64;
    int t  = threadIdx.x;
    int w  = t >> 6;
    int l  = t & 63;
    int g  = l >> 4;
    int ln = l & 15;

    // Q fragments (A-operand): lane holds Q[n0+16w+ln][kb*32 + g*8 + j]
    short8 qh[8], ql[8];
    {
        size_t base = (size_t)(b * NN + n0 + w * 16 + ln) * CC + g * 8;
#pragma unroll
        for (int kb = 0; kb < 8; ++kb) {
            qh[kb] = *(const short8*)&qhi[base + kb * 32];
            ql[kb] = *(const short8*)&qlo[base + kb * 32];
        }
    }

    f32x4 y[16];
#pragma unroll
    for (int ct = 0; ct < 16; ++ct) y[ct] = (f32x4){0.f, 0.f, 0.f, 0.f};
    float m_run[4] = {-1e30f, -1e30f, -1e30f, -1e30f};
    float l_run[4] = {0.f, 0.f, 0.f, 0.f};

    for (int kt = 0; kt < NN / TK; ++kt) {
        int m0 = kt * TK;
        __syncthreads();
        // stage K hi/lo: 32 rows * 512B each, 16B units
#pragma unroll
        for (int i = 0; i < 4; ++i) {
            int u = i * 256 + t;
            int row = u >> 5, col = (u & 31) * 8;
            size_t goff = (size_t)(b * NN + m0 + row) * CC + col;
            *(short8*)&kh_s[row][col] = *(const short8*)&khi[goff];
            *(short8*)&kl_s[row][col] = *(const short8*)&klo[goff];
        }
        // stage V^T from raw x (project to g on the fly)
#pragma unroll
        for (int i = 0; i < 8; ++i) {
            int u = i * 256 + t;
            int c = u >> 3, mq = (u & 7) * 4;
            const float4 v = *(const float4*)&x[(size_t)(b * CC + c) * NN + m0 + mq];
            float wg = w_g[c], bg = b_g[c];
            us4 o;
            o[0] = f2bf(v.x * wg + bg);
            o[1] = f2bf(v.y * wg + bg);
            o[2] = f2bf(v.z * wg + bg);
            o[3] = f2bf(v.w * wg + bg);
            *(us4*)&vt_s[c][mq] = o;
        }
        __syncthreads();

        // S = Q K^T  (2-term bf16 split: hi*hi + lo*hi + hi*lo)
        f32x4 s0 = (f32x4){0.f, 0.f, 0.f, 0.f};
        f32x4 s1 = (f32x4){0.f, 0.f, 0.f, 0.f};
#pragma unroll
        for (int kb = 0; kb < 8; ++kb) {
            short8 bh0 = *(const short8*)&kh_s[ln][kb * 32 + g * 8];
            short8 bl0 = *(const short8*)&kl_s[ln][kb * 32 + g * 8];
            s0 = MFMA16(qh[kb], bh0, s0);
            s0 = MFMA16(ql[kb], bh0, s0);
            s0 = MFMA16(qh[kb], bl0, s0);
            short8 bh1 = *(const short8*)&kh_s[16 + ln][kb * 32 + g * 8];
            short8 bl1 = *(const short8*)&kl_s[16 + ln][kb * 32 + g * 8];
            s1 = MFMA16(qh[kb], bh1, s1);
            s1 = MFMA16(ql[kb], bh1, s1);
            s1 = MFMA16(qh[kb], bl1, s1);
        }

        // online softmax: rows (4g+j) per lane group; reduce over m (lanes 0..15 of group)
        float aj[4];
#pragma unroll
        for (int j = 0; j < 4; ++j) {
            float v = fmaxf(s0[j], s1[j]);
            v = fmaxf(v, __shfl_xor(v, 1));
            v = fmaxf(v, __shfl_xor(v, 2));
            v = fmaxf(v, __shfl_xor(v, 4));
            v = fmaxf(v, __shfl_xor(v, 8));
            float mnew  = fmaxf(m_run[j], v);
            float alpha = __expf(m_run[j] - mnew);
            float p0 = __expf(s0[j] - mnew);
            float p1 = __expf(s1[j] - mnew);
            p_s[w][g * 4 + j][ln]      = f2bf(p0);
            p_s[w][g * 4 + j][16 + ln] = f2bf(p1);
            float ps = p0 + p1;
            ps += __shfl_xor(ps, 1);
            ps += __shfl_xor(ps, 2);
            ps += __shfl_xor(ps, 4);
            ps += __shfl_xor(ps, 8);
            l_run[j] = l_run[j] * alpha + ps;
            m_run[j] = mnew;
            aj[j] = alpha;
        }
#pragma unroll
        for (int ct = 0; ct < 16; ++ct) {
            y[ct][0] *= aj[0]; y[ct][1] *= aj[1];
            y[ct][2] *= aj[2]; y[ct][3] *= aj[3];
        }

        // PV: A = P (wave-private LDS round-trip), B = V^T chunks
        short8 pa = *(const short8*)&p_s[w][ln][g * 8];
#pragma unroll
        for (int ct = 0; ct < 16; ++ct) {
            short8 vb = *(const short8*)&vt_s[ct * 16 + ln][g * 8];
            y[ct] = MFMA16(pa, vb, y[ct]);
        }
    }

    // epilogue: y/l, fold out-proj+BN, add residual; out layout (B,C,N)
    float sc[16], bc[16];
#pragma unroll
    for (int ct = 0; ct < 16; ++ct) {
        int c = ct * 16 + ln;
        sc[ct] = s2b2[c];
        bc[ct] = s2b2[CC + c];
    }
#pragma unroll
    for (int j = 0; j < 4; ++j) {
        float inv = 1.0f / l_run[j];
        int n = n0 + w * 16 + g * 4 + j;
#pragma unroll
        for (int ct = 0; ct < 16; ++ct) {
            int c = ct * 16 + ln;
            size_t idx = (size_t)(b * CC + c) * NN + n;
            out[idx] = y[ct][j] * inv * sc[ct] + bc[ct] + x[idx];
        }
    }
}

extern "C" void kernel_launch(void* const* d_in, const int* in_sizes, int n_in,
                              void* d_out, int out_size, void* d_ws, size_t ws_size,
                              hipStream_t stream) {
    const float* x   = (const float*)d_in[0];
    const float* w_g = (const float*)d_in[1];
    const float* b_g = (const float*)d_in[2];
    const float* w_t = (const float*)d_in[3];
    const float* b_t = (const float*)d_in[4];
    const float* w_p = (const float*)d_in[5];
    const float* b_p = (const float*)d_in[6];
    const float* w_o = (const float*)d_in[7];
    const float* b_o = (const float*)d_in[8];
    const float* gam = (const float*)d_in[9];
    const float* bet = (const float*)d_in[10];
    const float* mea = (const float*)d_in[11];
    const float* var = (const float*)d_in[12];
    float* out = (float*)d_out;

    const size_t QSZ = (size_t)NB * NN * CC;  // elements per bf16 array
    unsigned short* qhi = (unsigned short*)d_ws;
    unsigned short* qlo = qhi + QSZ;
    unsigned short* khi = qlo + QSZ;
    unsigned short* klo = khi + QSZ;
    float* s2b2 = (float*)(klo + QSZ);

    prep_s2<<<1, 256, 0, stream>>>(w_o, b_o, gam, bet, mea, var, s2b2);
    prep_qk<<<NB * 36 * 4, 256, 0, stream>>>(x, w_t, b_t, w_p, b_p, qhi, qlo, khi, klo);
    attn<<<NB * 36, 256, 0, stream>>>(x, qhi, qlo, khi, klo, w_g, b_g, s2b2, out);
}

// Round 5
// 327.075 us; speedup vs baseline: 1.6379x; 1.6379x over previous
//
#include <hip/hip_runtime.h>

#define NB 8
#define CC 256
#define NN 2304
#define TK 32
#define QSZ ((size_t)NB * NN * CC)

typedef __attribute__((ext_vector_type(8))) short short8;
typedef __attribute__((ext_vector_type(4))) float f32x4;
typedef __attribute__((ext_vector_type(4))) unsigned short us4;

#define MFMA16(a, b, c) __builtin_amdgcn_mfma_f32_16x16x32_bf16((a), (b), (c), 0, 0, 0)

__device__ __forceinline__ unsigned short f2bf(float f) {
    unsigned int u = __float_as_uint(f);
    u = (u + 0x7fffu + ((u >> 16) & 1u)) >> 16;
    return (unsigned short)u;
}
__device__ __forceinline__ float bf2f(unsigned short h) {
    return __uint_as_float(((unsigned int)h) << 16);
}

// ---- fold output projection + BN into per-channel scale/bias ----
__global__ void prep_s2(const float* __restrict__ w_o, const float* __restrict__ b_o,
                        const float* __restrict__ gam, const float* __restrict__ bet,
                        const float* __restrict__ mea, const float* __restrict__ var,
                        float* __restrict__ s2b2) {
    int c = threadIdx.x;
    float inv = gam[c] * rsqrtf(var[c] + 1e-5f);
    s2b2[c]      = w_o[c] * inv;
    s2b2[CC + c] = b_o[c] * inv + bet[c] - mea[c] * inv;
}

// ---- V^T projection: vt[b][c][m] = bf16(x * w_g + b_g)  (x native layout, no transpose) ----
__global__ __launch_bounds__(256) void prep_v(const float* __restrict__ x,
                                              const float* __restrict__ w_g,
                                              const float* __restrict__ b_g,
                                              unsigned short* __restrict__ vt) {
    size_t i = ((size_t)blockIdx.x * 256 + threadIdx.x) * 8;
    int c = (int)((i / NN) % CC);
    float wg = w_g[c], bg = b_g[c];
    float4 a = *(const float4*)&x[i];
    float4 d = *(const float4*)&x[i + 4];
    us4 o0, o1;
    o0[0] = f2bf(a.x * wg + bg); o0[1] = f2bf(a.y * wg + bg);
    o0[2] = f2bf(a.z * wg + bg); o0[3] = f2bf(a.w * wg + bg);
    o1[0] = f2bf(d.x * wg + bg); o1[1] = f2bf(d.y * wg + bg);
    o1[2] = f2bf(d.z * wg + bg); o1[3] = f2bf(d.w * wg + bg);
    *(us4*)&vt[i]     = o0;
    *(us4*)&vt[i + 4] = o1;
}

// ---- transpose + project x -> Q(hi/lo), K(hi/lo), layout (B, N, C) bf16 ----
__global__ __launch_bounds__(256) void prep_qk(
    const float* __restrict__ x,
    const float* __restrict__ w_t, const float* __restrict__ b_t,
    const float* __restrict__ w_p, const float* __restrict__ b_p,
    unsigned short* __restrict__ qhi, unsigned short* __restrict__ qlo,
    unsigned short* __restrict__ khi, unsigned short* __restrict__ klo) {
    __shared__ float tile[64][65];
    int bid = blockIdx.x;
    int b  = bid / 144;
    int r  = bid % 144;
    int n0 = (r / 4) * 64;
    int c0 = (r % 4) * 64;
    int t  = threadIdx.x;
    int tx = t & 15, ty = t >> 4;

#pragma unroll
    for (int i = 0; i < 4; ++i) {
        int c = ty + i * 16;
        const float4 v = *(const float4*)&x[(size_t)(b * CC + c0 + c) * NN + n0 + tx * 4];
        tile[c][tx * 4 + 0] = v.x;
        tile[c][tx * 4 + 1] = v.y;
        tile[c][tx * 4 + 2] = v.z;
        tile[c][tx * 4 + 3] = v.w;
    }
    __syncthreads();
#pragma unroll
    for (int i = 0; i < 4; ++i) {
        int n = ty + i * 16;
        us4 qh, ql, kh, kl;
#pragma unroll
        for (int k = 0; k < 4; ++k) {
            int c = c0 + tx * 4 + k;
            float v  = tile[tx * 4 + k][n];
            float qv = v * w_t[c] + b_t[c];
            unsigned short h = f2bf(qv);
            qh[k] = h; ql[k] = f2bf(qv - bf2f(h));
            float kv = v * w_p[c] + b_p[c];
            h = f2bf(kv);
            kh[k] = h; kl[k] = f2bf(kv - bf2f(h));
        }
        size_t off = (size_t)(b * NN + n0 + n) * CC + c0 + tx * 4;
        *(us4*)&qhi[off] = qh;
        *(us4*)&qlo[off] = ql;
        *(us4*)&khi[off] = kh;
        *(us4*)&klo[off] = kl;
    }
}

// ---- flash attention with key-split: each block = 64 q-rows x keys_per keys ----
__global__ __launch_bounds__(256, 2) void attn(
    const unsigned short* __restrict__ qhi, const unsigned short* __restrict__ qlo,
    const unsigned short* __restrict__ khi, const unsigned short* __restrict__ klo,
    const unsigned short* __restrict__ vt,
    unsigned short* __restrict__ py, float2* __restrict__ pml,
    int keys_per) {
    __shared__ __align__(16) unsigned short kh_s[TK][264];
    __shared__ __align__(16) unsigned short kl_s[TK][264];
    __shared__ __align__(16) unsigned short vt_s[CC][40];
    __shared__ __align__(16) unsigned short p_s[4][16][40];

    int bid = blockIdx.x;
    int s  = bid / (NB * 36);
    int r  = bid % (NB * 36);
    int b  = r / 36;
    int n0 = (r % 36) * 64;
    int t  = threadIdx.x;
    int w  = t >> 6;
    int l  = t & 63;
    int g  = l >> 4;
    int ln = l & 15;
    int k0 = s * keys_per;

    short8 qh[8], ql[8];
    {
        size_t base = (size_t)(b * NN + n0 + w * 16 + ln) * CC + g * 8;
#pragma unroll
        for (int kb = 0; kb < 8; ++kb) {
            qh[kb] = *(const short8*)&qhi[base + kb * 32];
            ql[kb] = *(const short8*)&qlo[base + kb * 32];
        }
    }

    f32x4 y[16];
#pragma unroll
    for (int ct = 0; ct < 16; ++ct) y[ct] = (f32x4){0.f, 0.f, 0.f, 0.f};
    float m_run[4] = {-1e30f, -1e30f, -1e30f, -1e30f};
    float l_run[4] = {0.f, 0.f, 0.f, 0.f};

    for (int kt = 0; kt < keys_per / TK; ++kt) {
        int m0 = k0 + kt * TK;
        __syncthreads();
#pragma unroll
        for (int i = 0; i < 4; ++i) {
            int u = i * 256 + t;
            int row = u >> 5, col = (u & 31) * 8;
            size_t goff = (size_t)(b * NN + m0 + row) * CC + col;
            *(short8*)&kh_s[row][col] = *(const short8*)&khi[goff];
            *(short8*)&kl_s[row][col] = *(const short8*)&klo[goff];
        }
#pragma unroll
        for (int i = 0; i < 4; ++i) {
            int u = i * 256 + t;
            int c = u >> 2, mq = (u & 3) * 8;
            *(short8*)&vt_s[c][mq] = *(const short8*)&vt[(size_t)(b * CC + c) * NN + m0 + mq];
        }
        __syncthreads();

        // S = Q K^T with 6 independent accumulator chains (hh/lh/hl x 2 halves)
        f32x4 shh0 = (f32x4){0.f,0.f,0.f,0.f}, slh0 = shh0, shl0 = shh0;
        f32x4 shh1 = shh0, slh1 = shh0, shl1 = shh0;
#pragma unroll
        for (int kb = 0; kb < 8; ++kb) {
            short8 bh0 = *(const short8*)&kh_s[ln][kb * 32 + g * 8];
            short8 bl0 = *(const short8*)&kl_s[ln][kb * 32 + g * 8];
            short8 bh1 = *(const short8*)&kh_s[16 + ln][kb * 32 + g * 8];
            short8 bl1 = *(const short8*)&kl_s[16 + ln][kb * 32 + g * 8];
            shh0 = MFMA16(qh[kb], bh0, shh0);
            slh0 = MFMA16(ql[kb], bh0, slh0);
            shl0 = MFMA16(qh[kb], bl0, shl0);
            shh1 = MFMA16(qh[kb], bh1, shh1);
            slh1 = MFMA16(ql[kb], bh1, slh1);
            shl1 = MFMA16(qh[kb], bl1, shl1);
        }
        f32x4 s0 = (shh0 + slh0) + shl0;
        f32x4 s1 = (shh1 + slh1) + shl1;

        float aj[4];
#pragma unroll
        for (int j = 0; j < 4; ++j) {
            float v = fmaxf(s0[j], s1[j]);
            v = fmaxf(v, __shfl_xor(v, 1));
            v = fmaxf(v, __shfl_xor(v, 2));
            v = fmaxf(v, __shfl_xor(v, 4));
            v = fmaxf(v, __shfl_xor(v, 8));
            float mnew  = fmaxf(m_run[j], v);
            float alpha = __expf(m_run[j] - mnew);
            float p0 = __expf(s0[j] - mnew);
            float p1 = __expf(s1[j] - mnew);
            p_s[w][g * 4 + j][ln]      = f2bf(p0);
            p_s[w][g * 4 + j][16 + ln] = f2bf(p1);
            float ps = p0 + p1;
            ps += __shfl_xor(ps, 1);
            ps += __shfl_xor(ps, 2);
            ps += __shfl_xor(ps, 4);
            ps += __shfl_xor(ps, 8);
            l_run[j] = l_run[j] * alpha + ps;
            m_run[j] = mnew;
            aj[j] = alpha;
        }
#pragma unroll
        for (int ct = 0; ct < 16; ++ct) {
            y[ct][0] *= aj[0]; y[ct][1] *= aj[1];
            y[ct][2] *= aj[2]; y[ct][3] *= aj[3];
        }

        short8 pa = *(const short8*)&p_s[w][ln][g * 8];
#pragma unroll
        for (int ct = 0; ct < 16; ++ct) {
            short8 vb = *(const short8*)&vt_s[ct * 16 + ln][g * 8];
            y[ct] = MFMA16(pa, vb, y[ct]);
        }
    }

    // write unnormalized partial y (bf16) + per-row (m, l)
#pragma unroll
    for (int j = 0; j < 4; ++j) {
        int n = n0 + w * 16 + g * 4 + j;
        size_t rowb = ((size_t)(s * NB + b) * NN + n) * CC;
#pragma unroll
        for (int ct = 0; ct < 16; ++ct)
            py[rowb + ct * 16 + ln] = f2bf(y[ct][j]);
        if (ln == 0)
            pml[(size_t)(s * NB + b) * NN + n] = make_float2(m_run[j], l_run[j]);
    }
}

// ---- combine splits + out-proj/BN/residual; out layout (B,C,N) ----
__global__ __launch_bounds__(256) void combine(
    const unsigned short* __restrict__ py, const float2* __restrict__ pml,
    const float* __restrict__ x, const float* __restrict__ s2b2,
    float* __restrict__ out, int S) {
    __shared__ float ptile[64][65];
    int bid = blockIdx.x;
    int b  = bid / 36;
    int n0 = (bid % 36) * 64;
    int t  = threadIdx.x;
    int w  = t >> 6;
    int l  = t & 63;
    int n  = n0 + l;

    float M = -1e30f;
    for (int s = 0; s < S; ++s)
        M = fmaxf(M, pml[(size_t)(s * NB + b) * NN + n].x);
    float L = 0.f;
    for (int s = 0; s < S; ++s) {
        float2 ml = pml[(size_t)(s * NB + b) * NN + n];
        L += ml.y * __expf(ml.x - M);
    }

    float acc[64];
#pragma unroll
    for (int a = 0; a < 64; ++a) acc[a] = 0.f;

    for (int s = 0; s < S; ++s) {
        float wgt = __expf(pml[(size_t)(s * NB + b) * NN + n].x - M);
#pragma unroll
        for (int cc = 0; cc < 4; ++cc) {
            __syncthreads();
#pragma unroll
            for (int i = 0; i < 4; ++i) {
                int u = i * 256 + t;
                int row = u >> 4, c4 = (u & 15) * 4;
                us4 v = *(const us4*)&py[((size_t)(s * NB + b) * NN + n0 + row) * CC + cc * 64 + c4];
                ptile[row][c4 + 0] = bf2f(v[0]);
                ptile[row][c4 + 1] = bf2f(v[1]);
                ptile[row][c4 + 2] = bf2f(v[2]);
                ptile[row][c4 + 3] = bf2f(v[3]);
            }
            __syncthreads();
#pragma unroll
            for (int i = 0; i < 16; ++i)
                acc[cc * 16 + i] += wgt * ptile[l][w * 16 + i];
        }
    }

    float invL = 1.f / L;
#pragma unroll
    for (int cc = 0; cc < 4; ++cc) {
#pragma unroll
        for (int i = 0; i < 16; ++i) {
            int c = cc * 64 + w * 16 + i;
            size_t idx = ((size_t)b * CC + c) * NN + n;
            out[idx] = acc[cc * 16 + i] * invL * s2b2[c] + s2b2[CC + c] + x[idx];
        }
    }
}

extern "C" void kernel_launch(void* const* d_in, const int* in_sizes, int n_in,
                              void* d_out, int out_size, void* d_ws, size_t ws_size,
                              hipStream_t stream) {
    const float* x   = (const float*)d_in[0];
    const float* w_g = (const float*)d_in[1];
    const float* b_g = (const float*)d_in[2];
    const float* w_t = (const float*)d_in[3];
    const float* b_t = (const float*)d_in[4];
    const float* w_p = (const float*)d_in[5];
    const float* b_p = (const float*)d_in[6];
    const float* w_o = (const float*)d_in[7];
    const float* b_o = (const float*)d_in[8];
    const float* gam = (const float*)d_in[9];
    const float* bet = (const float*)d_in[10];
    const float* mea = (const float*)d_in[11];
    const float* var = (const float*)d_in[12];
    float* out = (float*)d_out;

    unsigned short* qhi = (unsigned short*)d_ws;
    unsigned short* qlo = qhi + QSZ;
    unsigned short* khi = qlo + QSZ;
    unsigned short* klo = khi + QSZ;
    unsigned short* vt  = klo + QSZ;
    float* s2b2 = (float*)(vt + QSZ);

    size_t base_b = 5 * QSZ * 2 + 2048;
    size_t per_b  = QSZ * 2 + (size_t)NB * NN * 8;
    int S = 1;
    if (base_b + 4 * per_b <= ws_size) S = 4;
    else if (base_b + 2 * per_b <= ws_size) S = 2;

    float2* pml = (float2*)((char*)d_ws + base_b);
    unsigned short* py = (unsigned short*)(pml + (size_t)S * NB * NN);

    prep_s2<<<1, 256, 0, stream>>>(w_o, b_o, gam, bet, mea, var, s2b2);
    prep_v<<<(int)(QSZ / 2048), 256, 0, stream>>>(x, w_g, b_g, vt);
    prep_qk<<<NB * 36 * 4, 256, 0, stream>>>(x, w_t, b_t, w_p, b_p, qhi, qlo, khi, klo);
    attn<<<NB * 36 * S, 256, 0, stream>>>(qhi, qlo, khi, klo, vt, py, pml, NN / S);
    combine<<<NB * 36, 256, 0, stream>>>(py, pml, x, s2b2, out, S);
}